// Round 7
// baseline (262.108 us; speedup 1.0000x reference)
//
#include <hip/hip_runtime.h>

#define HBITS 19u
#define HSIZE (1u << HBITS)
#define HMASK (HSIZE - 1u)
#define ECAP  (1 << 20)           // extras capacity (entries)
#define EMPTY64 0xFFFFFFFFFFFFFFFFull

constexpr int CD = 41, CH = 1024, CW = 1024;

// ---------------- setup: clear hash table, flags, counters ----------------

__global__ __launch_bounds__(256) void setup(unsigned long long* __restrict__ tab,
                                             int* __restrict__ flags, int n,
                                             int* __restrict__ cnt, int* __restrict__ scnt) {
    unsigned i = blockIdx.x * blockDim.x + threadIdx.x;
    if (i < HSIZE) tab[i] = EMPTY64;
    if (i < (unsigned)n) flags[i] = 0;
    if (i == 0) { *cnt = 0; *scnt = 0; }
}

// ---------------- hash: 64-bit records (idx<<32 | lin), linear probe ----------------

__global__ __launch_bounds__(256) void hash_insert(const int* __restrict__ coors, int n,
                                                   unsigned long long* __restrict__ tab) {
    int i = blockIdx.x * blockDim.x + threadIdx.x;
    if (i >= n) return;
    int b = coors[4 * i], z = coors[4 * i + 1], y = coors[4 * i + 2], x = coors[4 * i + 3];
    unsigned lin = (((unsigned)b * CD + (unsigned)z) * CH + (unsigned)y) * CW + (unsigned)x;
    unsigned h = (lin * 2654435761u) >> (32u - HBITS);
    unsigned long long rec = ((unsigned long long)(unsigned)i << 32) | (unsigned long long)lin;
    while (true) {
        unsigned long long prev = atomicCAS(&tab[h], EMPTY64, rec);
        if (prev == EMPTY64) break;
        h = (h + 1u) & HMASK;
    }
}

__device__ __forceinline__ int hash_lookup(unsigned lin, const unsigned long long* __restrict__ tab) {
    unsigned h = (lin * 2654435761u) >> (32u - HBITS);
    while (true) {
        unsigned long long v = tab[h];
        if ((unsigned)v == lin) return (int)(v >> 32);
        if (v == EMPTY64) return -1;
        h = (h + 1u) & HMASK;
    }
}

// ---------------- extras: one thread per (point, tap) pair ----------------
// 13 taps/point (mirror symmetry covers the other 13): thread does ONE lookup ->
// no in-order serialization of probes; ~24 waves/SIMD hides the round-trip latency.

__global__ __launch_bounds__(256) void build_extras_pairs(const int* __restrict__ coors, int n,
                                                          const unsigned long long* __restrict__ tab,
                                                          int2* __restrict__ extras,
                                                          int* __restrict__ cnt,
                                                          int* __restrict__ flags,
                                                          int* __restrict__ Slist,
                                                          int* __restrict__ scnt) {
    int tid = blockIdx.x * blockDim.x + threadIdx.x;
    if (tid >= n * 13) return;
    int i = tid / 13;
    int k = tid - i * 13;
    int b = coors[4 * i], z = coors[4 * i + 1], y = coors[4 * i + 2], x = coors[4 * i + 3];
    int dz = k / 9 - 1, dy = (k / 3) % 3 - 1, dx = k % 3 - 1;
    int nz = z + dz, ny = y + dy, nx = x + dx;
    if (nz < 0 || nz >= CD || ny < 0 || ny >= CH || nx < 0 || nx >= CW) return;
    unsigned lin = (((unsigned)b * CD + (unsigned)nz) * CH + (unsigned)ny) * CW + (unsigned)nx;
    int j = hash_lookup(lin, tab);
    if (j < 0) return;
    int pos = atomicAdd(cnt, 2);
    if (pos + 1 < ECAP) {
        extras[pos]     = make_int2((i << 5) | k,        j);
        extras[pos + 1] = make_int2((j << 5) | (26 - k), i);
        if (atomicExch(&flags[i], 1) == 0) Slist[atomicAdd(scnt, 1)] = i;
        if (atomicExch(&flags[j], 1) == 0) Slist[atomicAdd(scnt, 1)] = j;
    }
}

// ---------------- mm64: C = A @ B, 64x64 row-major ----------------

__global__ __launch_bounds__(256) void mm64(const float* __restrict__ A,
                                            const float* __restrict__ B,
                                            float* __restrict__ C) {
    int e = blockIdx.x * 256 + threadIdx.x;
    int r = e >> 6, c = e & 63;
    float s0 = 0.f, s1 = 0.f;
#pragma unroll
    for (int k = 0; k < 64; k += 2) {
        s0 = fmaf(A[r * 64 + k],     B[k * 64 + c],       s0);
        s1 = fmaf(A[r * 64 + k + 1], B[(k + 1) * 64 + c], s1);
    }
    C[e] = s0 + s1;
}

// ---------------- tiled row GEMM: out[p] = x[p] @ Wm (row-major [cin][cout]) --------
// 192 points/block (3 waves). X staged in LDS (coalesced float4 in, stride-65 pad ->
// compute reads 2-way bank = free). lane = point; acc[64] static. W rows via uniform
// s_load. Output bounced through LDS for coalesced float4 stores. (R5-verified form.)

#define GSTRIDE 65

__global__ __launch_bounds__(192, 2) void gemm_tile(const float* __restrict__ xin,
                                                    float* __restrict__ xout,
                                                    const float* __restrict__ Wm,
                                                    const int* __restrict__ list,     // null -> identity
                                                    const int* __restrict__ listCnt,  // null -> n
                                                    int n) {
    __shared__ float Xs[192 * GSTRIDE];   // 49,920 B
    int t = threadIdx.x;
    int lane = t & 63;
    int wv = t >> 6;
    int cnt = listCnt ? *listCnt : n;
    if (cnt <= 0) return;
    int ntiles = (cnt + 191) / 192;

    for (int tile = blockIdx.x; tile < ntiles; tile += gridDim.x) {
        int base = tile * 192;
        __syncthreads();                               // Xs reuse guard
#pragma unroll
        for (int it = 0; it < 16; ++it) {              // global -> LDS, coalesced
            int f = it * 192 + t;                      // float4 id 0..3071
            int row = f >> 4, c4 = f & 15;
            int gr = base + row;
            int src = gr < cnt ? gr : cnt - 1;
            if (list) src = list[src];
            float4 v = *(const float4*)(xin + (size_t)src * 64 + c4 * 4);
            float* d = &Xs[row * GSTRIDE + c4 * 4];
            d[0] = v.x; d[1] = v.y; d[2] = v.z; d[3] = v.w;
        }
        __syncthreads();

        int myrow = wv * 64 + lane;
        float* xr = &Xs[myrow * GSTRIDE];
        float acc[64];
#pragma unroll
        for (int o = 0; o < 64; ++o) acc[o] = 0.f;
#pragma unroll 4
        for (int c = 0; c < 64; ++c) {
            float xc = xr[c];
            const float* wr = Wm + c * 64;             // uniform -> s_load
#pragma unroll
            for (int o = 0; o < 64; ++o) acc[o] = fmaf(xc, wr[o], acc[o]);
        }
#pragma unroll
        for (int o = 0; o < 64; ++o) xr[o] = acc[o];   // own row only
        __syncthreads();
#pragma unroll
        for (int it = 0; it < 16; ++it) {              // LDS -> global, coalesced
            int f = it * 192 + t;
            int row = f >> 4, c4 = f & 15;
            int gr = base + row;
            if (gr < cnt) {
                int dst = list ? list[gr] : gr;
                const float* s = &Xs[row * GSTRIDE + c4 * 4];
                float4 v = make_float4(s[0], s[1], s[2], s[3]);
                *(float4*)(xout + (size_t)dst * 64 + c4 * 4) = v;
            }
        }
    }
}

// ---------------- sparse residual: out[i] += x[j] @ W[k] per extra entry ----------------

__global__ __launch_bounds__(256) void residual(const float* __restrict__ xin,
                                                float* __restrict__ xout,
                                                const float* __restrict__ Wl,   // [27][64][64]
                                                const int2* __restrict__ extras,
                                                const int* __restrict__ cnt) {
    int m = *cnt; if (m > ECAP) m = ECAP;
    int nw = (int)((gridDim.x * blockDim.x) >> 6);
    int gw = (int)((blockIdx.x * blockDim.x + threadIdx.x) >> 6);
    int lane = threadIdx.x & 63;
    for (int e = gw; e < m; e += nw) {
        int eu = __builtin_amdgcn_readfirstlane(e);
        int2 pr = extras[eu];
        int i = __builtin_amdgcn_readfirstlane(pr.x >> 5);
        int k = __builtin_amdgcn_readfirstlane(pr.x & 31);
        int j = __builtin_amdgcn_readfirstlane(pr.y);
        const float* xj = xin + (size_t)j * 64;
        const float* Wk = Wl + k * 4096 + lane;
        float a0 = 0.f, a1 = 0.f;
#pragma unroll
        for (int c = 0; c < 64; c += 2) {
            a0 = fmaf(xj[c],     Wk[c * 64],       a0);
            a1 = fmaf(xj[c + 1], Wk[(c + 1) * 64], a1);
        }
        atomicAdd(&xout[(size_t)i * 64 + lane], a0 + a1);
    }
}

// ---------------- launch ----------------

extern "C" void kernel_launch(void* const* d_in, const int* in_sizes, int n_in,
                              void* d_out, int out_size, void* d_ws, size_t ws_size,
                              hipStream_t stream) {
    const float* features = (const float*)d_in[0];
    const float* Ws       = (const float*)d_in[1];   // [3][27][64][64]
    const int*   coors    = (const int*)d_in[2];
    int n = in_sizes[0] / 64;

    char* p = (char*)d_ws;
    unsigned long long* tab = (unsigned long long*)p; p += (size_t)HSIZE * 8;
    int* cnt  = (int*)p;
    int* scnt = cnt + 1;                              p += 256;
    int2* extras = (int2*)p;                          p += (size_t)ECAP * 8;
    int* flags = (int*)p;                             p += (((size_t)n * 4 + 255) & ~255ull);
    int* Slist = (int*)p;                             p += (((size_t)n * 4 + 255) & ~255ull);
    float* bufA = (float*)p;                          p += (((size_t)n * 256 + 255) & ~255ull);
    float* bufB = (float*)p;                          p += (((size_t)n * 256 + 255) & ~255ull);
    float* T  = (float*)p;                            p += 16384;
    float* P  = (float*)p;                            p += 16384;
    float* out = (float*)d_out;

    const float* W0  = Ws + 0 * 27 * 4096;
    const float* W1  = Ws + 1 * 27 * 4096;
    const float* W2  = Ws + 2 * 27 * 4096;
    const float* W0c = W0 + 13 * 4096;
    const float* W1c = W1 + 13 * 4096;
    const float* W2c = W2 + 13 * 4096;

    setup<<<(HSIZE + 255) / 256, 256, 0, stream>>>(tab, flags, n, cnt, scnt);
    hash_insert<<<(n + 255) / 256, 256, 0, stream>>>(coors, n, tab);
    mm64<<<16, 256, 0, stream>>>(W0c, W1c, T);       // T = W0c @ W1c
    mm64<<<16, 256, 0, stream>>>(T, W2c, P);         // P = T @ W2c
    build_extras_pairs<<<(n * 13 + 255) / 256, 256, 0, stream>>>(coors, n, tab, extras, cnt,
                                                                 flags, Slist, scnt);

    // dense collapsed 3-layer pass: out = features @ P  (1 tile per block)
    int dtiles = (n + 191) / 192;
    gemm_tile<<<dtiles, 192, 0, stream>>>(features, out, P, nullptr, nullptr, n);

    // S-pass (closed set): per-layer propagation on S rows, then overwrite out rows.
    // Wide grids: idle blocks exit instantly; active blocks do <=1 tile.
    gemm_tile<<<128, 192, 0, stream>>>(features, bufA, W0c, Slist, scnt, n);
    residual<<<256, 256, 0, stream>>>(features, bufA, W0, extras, cnt);
    gemm_tile<<<128, 192, 0, stream>>>(bufA, bufB, W1c, Slist, scnt, n);
    residual<<<256, 256, 0, stream>>>(bufA, bufB, W1, extras, cnt);
    gemm_tile<<<128, 192, 0, stream>>>(bufB, out, W2c, Slist, scnt, n);
    residual<<<256, 256, 0, stream>>>(bufB, out, W2, extras, cnt);
}

// Round 8
// 162.960 us; speedup vs baseline: 1.6084x; 1.6084x over previous
//
#include <hip/hip_runtime.h>

#define HBITS 19u
#define HSIZE (1u << HBITS)
#define HMASK (HSIZE - 1u)
#define MAXD  27                  // geometric max neighbors (26) + slack
#define EMPTY64 0xFFFFFFFFFFFFFFFFull

constexpr int CD = 41, CH = 1024, CW = 1024;

// ---------------- setup: clear hash table + degree array ----------------

__global__ __launch_bounds__(256) void setup(unsigned long long* __restrict__ tab,
                                             int* __restrict__ deg, int n) {
    unsigned i = blockIdx.x * blockDim.x + threadIdx.x;
    if (i < HSIZE) tab[i] = EMPTY64;
    if (i < (unsigned)n) deg[i] = 0;
}

// ---------------- hash: 64-bit records (idx<<32 | lin), linear probe ----------------

__global__ __launch_bounds__(256) void hash_insert(const int* __restrict__ coors, int n,
                                                   unsigned long long* __restrict__ tab) {
    int i = blockIdx.x * blockDim.x + threadIdx.x;
    if (i >= n) return;
    int b = coors[4 * i], z = coors[4 * i + 1], y = coors[4 * i + 2], x = coors[4 * i + 3];
    unsigned lin = (((unsigned)b * CD + (unsigned)z) * CH + (unsigned)y) * CW + (unsigned)x;
    unsigned h = (lin * 2654435761u) >> (32u - HBITS);
    unsigned long long rec = ((unsigned long long)(unsigned)i << 32) | (unsigned long long)lin;
    while (true) {
        unsigned long long prev = atomicCAS(&tab[h], EMPTY64, rec);
        if (prev == EMPTY64) break;
        h = (h + 1u) & HMASK;
    }
}

__device__ __forceinline__ int hash_lookup(unsigned lin, const unsigned long long* __restrict__ tab) {
    unsigned h = (lin * 2654435761u) >> (32u - HBITS);
    while (true) {
        unsigned long long v = tab[h];
        if ((unsigned)v == lin) return (int)(v >> 32);
        if (v == EMPTY64) return -1;
        h = (h + 1u) & HMASK;
    }
}

// ---------------- adjacency build: one thread per (point, tap<13) ----------------
// mirror symmetry: finding (i,k,j) also records (j,26-k,i). Each undirected pair is
// found exactly once (reverse tap >= 14 is never scanned). ONLY scattered atomics.

__global__ __launch_bounds__(256) void build_adj(const int* __restrict__ coors, int n,
                                                 const unsigned long long* __restrict__ tab,
                                                 int* __restrict__ deg,
                                                 int* __restrict__ adj) {
    int tid = blockIdx.x * blockDim.x + threadIdx.x;
    if (tid >= n * 13) return;
    int i = tid / 13;
    int k = tid - i * 13;
    int b = coors[4 * i], z = coors[4 * i + 1], y = coors[4 * i + 2], x = coors[4 * i + 3];
    int dz = k / 9 - 1, dy = (k / 3) % 3 - 1, dx = k % 3 - 1;
    int nz = z + dz, ny = y + dy, nx = x + dx;
    if (nz < 0 || nz >= CD || ny < 0 || ny >= CH || nx < 0 || nx >= CW) return;
    unsigned lin = (((unsigned)b * CD + (unsigned)nz) * CH + (unsigned)ny) * CW + (unsigned)nx;
    int j = hash_lookup(lin, tab);
    if (j < 0) return;
    int si = atomicAdd(&deg[i], 1);
    if (si < MAXD) adj[(size_t)i * MAXD + si] = (j << 5) | k;
    int sj = atomicAdd(&deg[j], 1);
    if (sj < MAXD) adj[(size_t)j * MAXD + sj] = (i << 5) | (26 - k);
}

// ---------------- mm64: C = A @ B, 64x64 row-major ----------------

__global__ __launch_bounds__(256) void mm64(const float* __restrict__ A,
                                            const float* __restrict__ B,
                                            float* __restrict__ C) {
    int e = blockIdx.x * 256 + threadIdx.x;
    int r = e >> 6, c = e & 63;
    float s0 = 0.f, s1 = 0.f;
#pragma unroll
    for (int k = 0; k < 64; k += 2) {
        s0 = fmaf(A[r * 64 + k],     B[k * 64 + c],       s0);
        s1 = fmaf(A[r * 64 + k + 1], B[(k + 1) * 64 + c], s1);
    }
    C[e] = s0 + s1;
}

// ---------------- dense tile: out[p] = x[p] @ P, 192 points/block, 1 tile/block ----
// R5-verified form: LDS-staged X (coalesced float4 in, stride-65 pad -> compute reads
// 2-way bank = free). lane = point; acc[64] static. P rows via uniform s_load.

#define GSTRIDE 65

__global__ __launch_bounds__(192, 2) void dense_tile(const float* __restrict__ xin,
                                                     float* __restrict__ xout,
                                                     const float* __restrict__ P,
                                                     int n) {
    __shared__ float Xs[192 * GSTRIDE];   // 49,920 B
    int t = threadIdx.x;
    int lane = t & 63;
    int wv = t >> 6;
    int base = blockIdx.x * 192;

#pragma unroll
    for (int it = 0; it < 16; ++it) {               // global -> LDS, coalesced
        int f = it * 192 + t;                       // float4 id 0..3071
        int row = f >> 4, c4 = f & 15;
        int gr = base + row;
        int src = gr < n ? gr : n - 1;
        float4 v = *(const float4*)(xin + (size_t)src * 64 + c4 * 4);
        float* d = &Xs[row * GSTRIDE + c4 * 4];
        d[0] = v.x; d[1] = v.y; d[2] = v.z; d[3] = v.w;
    }
    __syncthreads();

    int myrow = wv * 64 + lane;
    float* xr = &Xs[myrow * GSTRIDE];
    float acc[64];
#pragma unroll
    for (int o = 0; o < 64; ++o) acc[o] = 0.f;
#pragma unroll 4
    for (int c = 0; c < 64; ++c) {
        float xc = xr[c];
        const float* wr = P + c * 64;               // uniform -> s_load
#pragma unroll
        for (int o = 0; o < 64; ++o) acc[o] = fmaf(xc, wr[o], acc[o]);
    }
#pragma unroll
    for (int o = 0; o < 64; ++o) xr[o] = acc[o];    // own row only
    __syncthreads();
#pragma unroll
    for (int it = 0; it < 16; ++it) {               // LDS -> global, coalesced
        int f = it * 192 + t;
        int row = f >> 4, c4 = f & 15;
        int gr = base + row;
        if (gr < n) {
            const float* s = &Xs[row * GSTRIDE + c4 * 4];
            float4 v = make_float4(s[0], s[1], s[2], s[3]);
            *(float4*)(xout + (size_t)gr * 64 + c4 * 4) = v;
        }
    }
}

// ---------------- fused S-layer: for points with deg>0, full layer = center + taps --
// Wave scans 64 points with ONE coalesced deg load + ballot; for each hit: center
// matvec + deg[i] neighbor matvecs (shfl-broadcast x, coalesced W rows). No atomics.

__global__ __launch_bounds__(256) void s_layer(const float* __restrict__ xin,
                                               float* __restrict__ xout,
                                               const float* __restrict__ Wl,   // [27][64][64]
                                               const int* __restrict__ deg,
                                               const int* __restrict__ adj,
                                               int n) {
    int wv  = (int)((blockIdx.x * blockDim.x + threadIdx.x) >> 6);
    int nwv = (int)((gridDim.x * blockDim.x) >> 6);
    int lane = threadIdx.x & 63;
    int nchunk = (n + 63) >> 6;
    const float* Wc = Wl + 13 * 4096;

    for (int ch = wv; ch < nchunk; ch += nwv) {
        int base = ch << 6;
        int p = base + lane;
        int dl = (p < n) ? deg[p] : 0;
        unsigned long long m = __ballot(dl != 0);
        while (m) {
            int bpos = (int)__ffsll(m) - 1;
            m &= m - 1;
            int i = base + bpos;
            int d = __shfl(dl, bpos);
            if (d > MAXD) d = MAXD;
            float xi = xin[(size_t)i * 64 + lane];
            float a0 = 0.f, a1 = 0.f;
#pragma unroll
            for (int c = 0; c < 64; c += 2) {
                a0 = fmaf(__shfl(xi, c),     Wc[c * 64 + lane],       a0);
                a1 = fmaf(__shfl(xi, c + 1), Wc[(c + 1) * 64 + lane], a1);
            }
            for (int e = 0; e < d; ++e) {
                int ent = adj[(size_t)i * MAXD + e];    // uniform -> broadcast
                int j = ent >> 5, k = ent & 31;
                float xj = xin[(size_t)j * 64 + lane];
                const float* Wk = Wl + k * 4096;
#pragma unroll
                for (int c = 0; c < 64; c += 2) {
                    a0 = fmaf(__shfl(xj, c),     Wk[c * 64 + lane],       a0);
                    a1 = fmaf(__shfl(xj, c + 1), Wk[(c + 1) * 64 + lane], a1);
                }
            }
            xout[(size_t)i * 64 + lane] = a0 + a1;
        }
    }
}

// ---------------- launch ----------------

extern "C" void kernel_launch(void* const* d_in, const int* in_sizes, int n_in,
                              void* d_out, int out_size, void* d_ws, size_t ws_size,
                              hipStream_t stream) {
    const float* features = (const float*)d_in[0];
    const float* Ws       = (const float*)d_in[1];   // [3][27][64][64]
    const int*   coors    = (const int*)d_in[2];
    int n = in_sizes[0] / 64;

    char* p = (char*)d_ws;
    unsigned long long* tab = (unsigned long long*)p; p += (size_t)HSIZE * 8;
    int* deg = (int*)p;                               p += (((size_t)n * 4 + 255) & ~255ull);
    int* adj = (int*)p;                               p += (((size_t)n * MAXD * 4 + 255) & ~255ull);
    float* bufA = (float*)p;                          p += (((size_t)n * 256 + 255) & ~255ull);
    float* bufB = (float*)p;                          p += (((size_t)n * 256 + 255) & ~255ull);
    float* T  = (float*)p;                            p += 16384;
    float* P  = (float*)p;                            p += 16384;
    float* out = (float*)d_out;

    const float* W0  = Ws + 0 * 27 * 4096;
    const float* W1  = Ws + 1 * 27 * 4096;
    const float* W2  = Ws + 2 * 27 * 4096;
    const float* W0c = W0 + 13 * 4096;
    const float* W1c = W1 + 13 * 4096;
    const float* W2c = W2 + 13 * 4096;

    setup<<<(HSIZE + 255) / 256, 256, 0, stream>>>(tab, deg, n);
    hash_insert<<<(n + 255) / 256, 256, 0, stream>>>(coors, n, tab);
    mm64<<<16, 256, 0, stream>>>(W0c, W1c, T);       // T = W0c @ W1c
    mm64<<<16, 256, 0, stream>>>(T, W2c, P);         // P = T @ W2c
    build_adj<<<(n * 13 + 255) / 256, 256, 0, stream>>>(coors, n, tab, deg, adj);

    // dense collapsed 3-layer pass: out = features @ P (1 tile per block)
    int dtiles = (n + 191) / 192;
    dense_tile<<<dtiles, 192, 0, stream>>>(features, out, P, n);

    // S-pass (closed set, deg>0): fused center+taps per layer; overwrites out rows
    s_layer<<<512, 256, 0, stream>>>(features, bufA, W0, deg, adj, n);
    s_layer<<<512, 256, 0, stream>>>(bufA, bufB, W1, deg, adj, n);
    s_layer<<<512, 256, 0, stream>>>(bufB, out, W2, deg, adj, n);
}